// Round 8
// baseline (362.887 us; speedup 1.0000x reference)
//
#include <hip/hip_runtime.h>

#define USH unsigned short

// ---------- bf16 helpers (storage = unsigned short) ----------
__device__ __forceinline__ float b2f(USH u) {
    union { unsigned int i; float f; } x; x.i = ((unsigned int)u) << 16; return x.f;
}
__device__ __forceinline__ USH f2b(float f) {
    union { float f; unsigned int i; } x; x.f = f;
    unsigned int r = x.i + (0x7fffu + ((x.i >> 16) & 1u));  // RNE
    return (USH)(r >> 16);
}
__device__ __forceinline__ float ldf(const USH* p)  { return b2f(*p); }
__device__ __forceinline__ float ldf(const float* p){ return *p; }
__device__ __forceinline__ void stf(USH* p, float v)  { *p = f2b(v); }
__device__ __forceinline__ void stf(float* p, float v){ *p = v; }

// async global->LDS, 16B per lane (dest = wave-uniform base + lane*16)
#define GLOAD16(gp, lp) __builtin_amdgcn_global_load_lds(                     \
    (const __attribute__((address_space(1))) void*)(gp),                      \
    (__attribute__((address_space(3))) void*)(lp), 16, 0, 0)

typedef __attribute__((ext_vector_type(8))) __bf16 bf16x8;
typedef __attribute__((ext_vector_type(4))) float  floatx4;

// =====================================================================
// Weight transpose+convert: W[K][N] f32 -> WT[N][K] bf16.
// =====================================================================
__global__ __launch_bounds__(256) void transpose_f2b(const float* __restrict__ W,
                                                     USH* __restrict__ WT,
                                                     int K, int N) {
    __shared__ USH t[64][72];
    int n0 = blockIdx.x * 64, k0 = blockIdx.y * 64;
    int tid = threadIdx.x;
    int kr = tid >> 4, nc = (tid & 15) * 4;
#pragma unroll
    for (int r = 0; r < 4; r++) {
        int k = kr + r * 16;
        float4 v = *(const float4*)(W + (size_t)(k0 + k) * N + n0 + nc);
        t[nc + 0][k] = f2b(v.x); t[nc + 1][k] = f2b(v.y);
        t[nc + 2][k] = f2b(v.z); t[nc + 3][k] = f2b(v.w);
    }
    __syncthreads();
    int nr = tid >> 2, kc = (tid & 3) * 8;
#pragma unroll
    for (int r = 0; r < 2; r++) {
        int k = kc + r * 32;
        *(int4*)(WT + (size_t)(n0 + nr) * K + k0 + k) = *(const int4*)&t[nr][k];
    }
}

// =====================================================================
// LayerNorm rows of 1024. block=256, one block/row.
// =====================================================================
template <typename TX>
__global__ __launch_bounds__(256) void ln_rows(const TX* __restrict__ x,
                                               const float* __restrict__ g,
                                               const float* __restrict__ bb,
                                               USH* __restrict__ y) {
    int row = blockIdx.x, tid = threadIdx.x;
    const TX* xr = x + (size_t)row * 1024 + tid * 4;
    float v[4];
#pragma unroll
    for (int i = 0; i < 4; i++) v[i] = ldf(xr + i);
    float s  = v[0] + v[1] + v[2] + v[3];
    float ss = v[0]*v[0] + v[1]*v[1] + v[2]*v[2] + v[3]*v[3];
#pragma unroll
    for (int o = 32; o; o >>= 1) { s += __shfl_down(s, o); ss += __shfl_down(ss, o); }
    __shared__ float red[10];
    int w = tid >> 6;
    if ((tid & 63) == 0) { red[w] = s; red[4 + w] = ss; }
    __syncthreads();
    if (tid == 0) {
        float S = red[0] + red[1] + red[2] + red[3];
        float SS = red[4] + red[5] + red[6] + red[7];
        float mean = S * (1.f / 1024.f);
        float var  = SS * (1.f / 1024.f) - mean * mean;
        red[8] = mean; red[9] = rsqrtf(var + 1e-5f);
    }
    __syncthreads();
    float mean = red[8], rstd = red[9];
    USH* yr = y + (size_t)row * 1024 + tid * 4;
#pragma unroll
    for (int i = 0; i < 4; i++) {
        int c = tid * 4 + i;
        yr[i] = f2b((v[i] - mean) * rstd * g[c] + bb[c]);
    }
}

// =====================================================================
// zh = z @ wca + bca, emitting packed MFMA operand rows (head-major),
// exp2-domain fold (gvl = softplus(gamma)*log2e).
// =====================================================================
__global__ __launch_bounds__(256) void zh_kernel(const float* __restrict__ z,
                                                 const float* __restrict__ wca,
                                                 const float* __restrict__ bca,
                                                 const float* __restrict__ gamma,
                                                 USH* __restrict__ zq_pack,
                                                 USH* __restrict__ zk_pack) {
    int row = blockIdx.x, n = threadIdx.x;
    __shared__ float zrow[64];
    if (n < 64) zrow[n] = z[(size_t)row * 64 + n];
    __syncthreads();
    float s = bca[n];
#pragma unroll 8
    for (int k = 0; k < 64; k++) s = fmaf(zrow[k], wca[(size_t)k * 256 + n], s);
    int h = n >> 4, c = n & 15;
    float gvl = log1pf(__expf(gamma[h])) * 1.44269504f;  // softplus * log2e
    USH u = f2b(s);
    float sv = b2f(u);
    float sq = sv * sv;
    sq += __shfl_xor(sq, 1); sq += __shfl_xor(sq, 2);
    sq += __shfl_xor(sq, 4); sq += __shfl_xor(sq, 8);
    size_t base = ((size_t)h * 4096 + row) * 32;
    zk_pack[base + c] = u;
    zq_pack[base + c] = f2b(2.f * gvl * s);
    if (c == 0) {
        USH hi = f2b(sq);
        float lo = sq - b2f(hi);
        unsigned int kw0 = 0x3F80u | ((unsigned int)hi << 16);
        unsigned int kw1 = (unsigned int)f2b(lo);
        uint4 kv = {kw0, kw1, 0u, 0u};
        uint4 zz = {0u, 0u, 0u, 0u};
        *(uint4*)(zk_pack + base + 16) = kv;
        *(uint4*)(zk_pack + base + 24) = zz;
        unsigned int qw0 = (unsigned int)f2b(-gvl * sq) | ((unsigned int)f2b(-gvl) << 16);
        unsigned int qw1 = (unsigned int)f2b(-gvl);
        uint4 qv = {qw0, qw1, 0u, 0u};
        *(uint4*)(zq_pack + base + 16) = qv;
        *(uint4*)(zq_pack + base + 24) = zz;
    }
}

// =====================================================================
// MFMA GEMM v6: templated BK (64 or 128), XOR-swizzled gload_lds staging.
// KB=128 for the grid-capped N=1024 GEMMs; KB=64 for FFN1 (occupancy).
// EPI: 0 = plain | 1 = +res | 2 = gelu | 3 = +res
// =====================================================================
template <int EPI, int MI, int NI, int KB, typename TRES, typename TOUT>
__global__ __launch_bounds__(256) void gemm_kernel(const USH* __restrict__ A,
                                                   const USH* __restrict__ WT,
                                                   const float* __restrict__ bias,
                                                   const TRES* __restrict__ res,
                                                   TOUT* __restrict__ out,
                                                   int M, int N, int K) {
    constexpr int BM  = MI * 32;
    constexpr int BN  = NI * 32;
    constexpr int GR  = KB / 8;        // 16B granules per row
    constexpr int RPC = 2048 / KB;     // rows per 4KB staged chunk
    constexpr int ACH = BM / RPC;      // A chunks per K-step
    constexpr int BCH = BN / RPC;      // B chunks per K-step
    __shared__ __align__(16) USH lA[BM][KB];
    __shared__ __align__(16) USH lB[BN][KB];
    int tid = threadIdx.x;
    int lane = tid & 63, wave = tid >> 6;
    int wr = wave >> 1, wc = wave & 1;
    int quad = lane >> 4, l15 = lane & 15;
    int m0 = blockIdx.x * BM, n0 = blockIdx.y * BN;

    int srow = tid / GR;               // row within chunk
    int kg   = tid % GR;               // 16B granule within row
    int scol = (kg ^ (srow & 7)) * 8;  // swizzled source column

    const USH* gA = A + (size_t)(m0 + srow) * K + scol;
    const USH* gB = WT + (size_t)(n0 + srow) * K + scol;
    USH* lA0 = &lA[0][0] + tid * 8;    // lane*16B dest (linear)
    USH* lB0 = &lB[0][0] + tid * 8;
    int xo = (l15 & 7) * 8;            // read-side XOR

    floatx4 acc[MI][NI] = {};

    for (int k0 = 0; k0 < K; k0 += KB) {
#pragma unroll
        for (int c = 0; c < ACH; c++)
            GLOAD16(gA + (size_t)c * RPC * K + k0, lA0 + c * 2048);
#pragma unroll
        for (int c = 0; c < BCH; c++)
            GLOAD16(gB + (size_t)c * RPC * K + k0, lB0 + c * 2048);
        __syncthreads();

#pragma unroll
        for (int ks = 0; ks < KB / 32; ks++) {
            bf16x8 bfr[NI];
#pragma unroll
            for (int ni = 0; ni < NI; ni++)
                bfr[ni] = *(const bf16x8*)&lB[wc * (NI * 16) + ni * 16 + l15][(ks * 32 + quad * 8) ^ xo];
#pragma unroll
            for (int mi = 0; mi < MI; mi++) {
                bf16x8 afr = *(const bf16x8*)&lA[wr * (MI * 16) + mi * 16 + l15][(ks * 32 + quad * 8) ^ xo];
#pragma unroll
                for (int ni = 0; ni < NI; ni++)
                    acc[mi][ni] = __builtin_amdgcn_mfma_f32_16x16x32_bf16(afr, bfr[ni], acc[mi][ni], 0, 0, 0);
            }
        }
        __syncthreads();
    }

    float bias_v[NI];
#pragma unroll
    for (int ni = 0; ni < NI; ni++) bias_v[ni] = bias[n0 + wc * (NI * 16) + ni * 16 + l15];

#pragma unroll
    for (int mi = 0; mi < MI; mi++) {
#pragma unroll
        for (int r = 0; r < 4; r++) {
            int row = m0 + wr * (MI * 16) + mi * 16 + quad * 4 + r;
            size_t base = (size_t)row * N;
#pragma unroll
            for (int ni = 0; ni < NI; ni++) {
                int col = n0 + wc * (NI * 16) + ni * 16 + l15;
                float v = acc[mi][ni][r] + bias_v[ni];
                if (EPI == 2) {
                    // tanh-form GELU: v * sigmoid(1.5958*v + 0.07135*v^3)
                    float t = v * v;
                    float a = fmaf(t, -0.0713548162726f, -1.59576912161f);
                    v = v * __builtin_amdgcn_rcpf(1.f + __expf(v * a));
                }
                if (EPI == 1 || EPI == 3) v += ldf(res + base + col);
                stf(out + base + col, v);
            }
        }
    }
}

// =====================================================================
// Flash distance-attention v12: exp2-domain fold, MFMA rowsum.
// v12 vs v11: OCCUPANCY. Grid 512 blocks was a hard 2-blocks/CU cap
// (33% occupancy, all pipes <60% -> latency-bound). Now:
//  - q-split: 64 q-rows/block, grid (32, 32) = 1024 blocks.
//  - 8 waves keep working via KEY-split: wave wq -> q-subtile qw=wq&3,
//    key-half kg=wq>>2 (32 of the 64 keys/tile). Per-wave: 2 QK MFMA,
//    8 exp2, 1-dword P write/row, 5 PV MFMA. Partial (oacc,lacc) merged
//    through LDS at the end (one-time).
//  - Qb dropped entirely: it was staged once and read once; Q fragment
//    now loads directly from global.
//  - LDS 38.9 KB -> 4 blocks/CU -> 32 waves/CU (2x resident waves).
// sigma-perm per key-group: col = (key>>5)*32 + 2*(key&15) + ((key>>4)&1);
// V packs key pairs (k, k+16) per dword; P packs its 2 key-fragments per
// dword; all b128 reads keep 4-aligned bank starts.
// =====================================================================
__global__ __launch_bounds__(512) void attn12_kernel(const USH* __restrict__ zq_pack,
                                                     const USH* __restrict__ zk_pack,
                                                     const USH* __restrict__ value,
                                                     USH* __restrict__ attn_out) {
    int b = blockIdx.x >> 4, h = blockIdx.x & 15;
    int q0 = blockIdx.y * 64;
    int tid = threadIdx.x, lane = tid & 63, wq = tid >> 6;   // wq 0..7
    int qw = wq & 3, kg = wq >> 2;                           // q-subtile / key-half
    int quad = lane >> 4, l15 = lane & 15;

    // smem layout: VbT[2][64][72] @0 (18432B) | KbT[2][64][40] @18432
    // (10240B) | Pb[8][16][40] @28672 (10240B). Total 38912 B.
    // Merge overlay (after main loop; VbT/KbT dead): mrg[256][21] f32 @0.
    __shared__ __align__(16) char smem[38912];
    typedef USH VbT_t[64][72];
    typedef USH KbT_t[64][40];
    typedef USH Pb_t[16][40];
    VbT_t* VbT = reinterpret_cast<VbT_t*>(smem);
    KbT_t* KbT = reinterpret_cast<KbT_t*>(smem + 18432);
    Pb_t*  Pb  = reinterpret_cast<Pb_t*>(smem + 28672);
    float (*mrg)[21] = reinterpret_cast<float(*)[21]>(smem);

    const size_t zrow0 = (size_t)b * 2048;
    const USH* zq = zq_pack + ((size_t)h * 4096 + zrow0) * 32;
    const USH* zk = zk_pack + ((size_t)h * 4096 + zrow0) * 32;
    const size_t vbase = zrow0 * 1024 + h * 64;

    // Q fragment direct from global (read exactly once -- no LDS stage)
    bf16x8 afragQ = *(const bf16x8*)(zq + (size_t)(q0 + qw * 16 + l15) * 32 + quad * 8);

    // ones fragment (bf16 1.0 x8)
    union { unsigned int u[4]; bf16x8 v; } onesu;
#pragma unroll
    for (int i = 0; i < 4; i++) onesu.u[i] = 0x3F803F80u;
    bf16x8 ones = onesu.v;

    floatx4 oacc[4] = {};
    floatx4 lacc = {};

    // staging roles: tid<256 -> V loader; tid>=256 -> K loader
    int kp   = tid & 31;
    int va   = kp & 15, vb = kp >> 4;
    int vrow = va + vb * 32;            // keys vrow, vrow+16 per thread
    int dh0  = (tid >> 5) * 8;          // 8 dh values per thread
    int cb   = vb * 32 + va * 2;        // sigma col (USH) of key vrow
    int krow = (tid - 256) >> 2, kc0 = ((tid - 256) & 3) * 8;
    int4 vta, vtb; uint4 kreg;

    // ---- prologue: tile 0 -> LDS buf0; tile 1 -> regs ----
    if (tid < 256) {
        const USH* s0 = value + vbase + (size_t)vrow * 1024 + dh0;
        vta = *(const int4*)s0;
        vtb = *(const int4*)(s0 + 16 * 1024);
        const USH* ua = (const USH*)&vta;
        const USH* ub = (const USH*)&vtb;
#pragma unroll
        for (int e = 0; e < 8; e++) {
            unsigned int dw = (unsigned int)ua[e] | ((unsigned int)ub[e] << 16);
            *(unsigned int*)&VbT[0][dh0 + e][cb] = dw;
        }
        const USH* s1 = value + vbase + (size_t)(64 + vrow) * 1024 + dh0;
        vta = *(const int4*)s1;
        vtb = *(const int4*)(s1 + 16 * 1024);
    } else {
        kreg = *(const uint4*)(zk + (size_t)krow * 32 + kc0);
        *(uint4*)&KbT[0][krow][kc0] = kreg;
        kreg = *(const uint4*)(zk + (size_t)(64 + krow) * 32 + kc0);
    }

    for (int it = 0; it < 32; it++) {
        int cur = it & 1;
        __syncthreads();   // tile `it` staged; prev tile's reads done
        // ---- write tile it+1 into buf^1; issue loads for tile it+2 ----
        if (it + 1 < 32) {
            if (tid < 256) {
                const USH* ua = (const USH*)&vta;
                const USH* ub = (const USH*)&vtb;
#pragma unroll
                for (int e = 0; e < 8; e++) {
                    unsigned int dw = (unsigned int)ua[e] | ((unsigned int)ub[e] << 16);
                    *(unsigned int*)&VbT[cur ^ 1][dh0 + e][cb] = dw;
                }
                if (it + 2 < 32) {
                    const USH* s0 = value + vbase + (size_t)((it + 2) * 64 + vrow) * 1024 + dh0;
                    vta = *(const int4*)s0;
                    vtb = *(const int4*)(s0 + 16 * 1024);
                }
            } else {
                *(uint4*)&KbT[cur ^ 1][krow][kc0] = kreg;
                if (it + 2 < 32)
                    kreg = *(const uint4*)(zk + (size_t)((it + 2) * 64 + krow) * 32 + kc0);
            }
        }

        // ---- QK^T: this wave's 32 keys (key-half kg) ----
        bf16x8 bk0 = *(const bf16x8*)&KbT[cur][(kg * 2 + 0) * 16 + l15][quad * 8];
        bf16x8 bk1 = *(const bf16x8*)&KbT[cur][(kg * 2 + 1) * 16 + l15][quad * 8];
        floatx4 z0 = {}, z1 = {};
        floatx4 s0 = __builtin_amdgcn_mfma_f32_16x16x32_bf16(afragQ, bk0, z0, 0, 0, 0);
        floatx4 s1 = __builtin_amdgcn_mfma_f32_16x16x32_bf16(afragQ, bk1, z1, 0, 0, 0);

        // ---- softmax weights; packed P write (1 dword per row) ----
        // key kg*32 + j*16 + l15 -> local sigma col 2*l15 + j
#pragma unroll
        for (int r = 0; r < 4; r++) {
            union { float f; unsigned int i; } c0, c1;
            c0.f = exp2f(s0[r]); c1.f = exp2f(s1[r]);
            unsigned int dw = (c0.i >> 16) | (c1.i & 0xFFFF0000u);
            *(unsigned int*)&Pb[wq][quad * 4 + r][l15 * 2] = dw;
        }

        // ---- PV + rowsum over this wave's 32 keys ----
        bf16x8 bv[4];
#pragma unroll
        for (int nd = 0; nd < 4; nd++)
            bv[nd] = *(const bf16x8*)&VbT[cur][nd * 16 + l15][kg * 32 + quad * 8];
        bf16x8 ap = *(const bf16x8*)&Pb[wq][l15][quad * 8];
#pragma unroll
        for (int nd = 0; nd < 4; nd++)
            oacc[nd] = __builtin_amdgcn_mfma_f32_16x16x32_bf16(ap, bv[nd], oacc[nd], 0, 0, 0);
        lacc = __builtin_amdgcn_mfma_f32_16x16x32_bf16(ap, ones, lacc, 0, 0, 0);
    }

    // ---- merge key-half partials: kg=1 -> LDS -> kg=0 adds ----
    __syncthreads();                     // all LDS staging reads complete
    if (kg == 1) {
        float* m = mrg[qw * 64 + lane];
#pragma unroll
        for (int nd = 0; nd < 4; nd++)
#pragma unroll
            for (int r = 0; r < 4; r++) m[nd * 4 + r] = oacc[nd][r];
#pragma unroll
        for (int r = 0; r < 4; r++) m[16 + r] = lacc[r];
    }
    __syncthreads();
    if (kg == 0) {
        const float* m = mrg[qw * 64 + lane];
#pragma unroll
        for (int nd = 0; nd < 4; nd++)
#pragma unroll
            for (int r = 0; r < 4; r++) oacc[nd][r] += m[nd * 4 + r];
#pragma unroll
        for (int r = 0; r < 4; r++) {
            float inv = 1.f / (lacc[r] + m[16 + r]);
            int row = q0 + qw * 16 + quad * 4 + r;
            USH* o = attn_out + (zrow0 + row) * 1024 + h * 64;
#pragma unroll
            for (int nd = 0; nd < 4; nd++) o[nd * 16 + l15] = f2b(oacc[nd][r] * inv);
        }
    }
}

// =====================================================================
// z_out = LN(z + z_next) over rows of 64. block = 64 (one wave) per row.
// =====================================================================
__global__ __launch_bounds__(64) void lnc_kernel(const float* __restrict__ z,
                                                 const float* __restrict__ zn,
                                                 const float* __restrict__ g,
                                                 const float* __restrict__ bb,
                                                 float* __restrict__ out) {
    int row = blockIdx.x, t = threadIdx.x;
    float v = z[(size_t)row * 64 + t] + zn[(size_t)row * 64 + t];
    float s = v, ss = v * v;
#pragma unroll
    for (int o = 32; o; o >>= 1) { s += __shfl_xor(s, o); ss += __shfl_xor(ss, o); }
    float mean = s * (1.f / 64.f);
    float rstd = rsqrtf(ss * (1.f / 64.f) - mean * mean + 1e-5f);
    out[(size_t)row * 64 + t] = (v - mean) * rstd * g[t] + bb[t];
}

// =====================================================================
extern "C" void kernel_launch(void* const* d_in, const int* in_sizes, int n_in,
                              void* d_out, int out_size, void* d_ws, size_t ws_size,
                              hipStream_t stream) {
    // workspace layout (61 MB):
    //   [0,8M)    value    [8,16M) attn_o    [16,20M) zq_pack
    //   [20,24M)  zk_pack  [24,32M) hn
    //   [0,32M)   mid (overlays, written step 8)
    //   [32,40M)  hn2   [40,41M) znext
    //   [41,43M)  wvT  [43,45M) woT  [45,53M) w1T  [53,61M) w2T
    //   wcnT (128K) borrows the head of attn_o: written step 0, read
    //   step 4, overwritten step 5.
    // h1 (f32) lives in d_out's h region.
    char* p = (char*)d_ws;
    USH*   value   = (USH*)(p);
    USH*   attn_o  = (USH*)(p + ((size_t)8  << 20));
    USH*   wcnT    = (USH*)(p + ((size_t)8  << 20));   // overlay, pre-step-5
    USH*   zq_pack = (USH*)(p + ((size_t)16 << 20));
    USH*   zk_pack = (USH*)(p + ((size_t)20 << 20));
    USH*   hn      = (USH*)(p + ((size_t)24 << 20));
    USH*   mid     = (USH*)(p);
    USH*   hn2     = (USH*)(p + ((size_t)32 << 20));
    float* znext   = (float*)(p + ((size_t)40 << 20));
    USH*   wvT     = (USH*)(p + ((size_t)41 << 20));
    USH*   woT     = (USH*)(p + ((size_t)43 << 20));
    USH*   w1T     = (USH*)(p + ((size_t)45 << 20));
    USH*   w2T     = (USH*)(p + ((size_t)53 << 20));

    const float *h    = (const float*)d_in[0],  *z    = (const float*)d_in[1];
    const float *wv   = (const float*)d_in[2],  *bv   = (const float*)d_in[3];
    const float *wca  = (const float*)d_in[4],  *bca  = (const float*)d_in[5];
    const float *wcn  = (const float*)d_in[6],  *bcn  = (const float*)d_in[7];
    const float *wo   = (const float*)d_in[8],  *bo   = (const float*)d_in[9];
    const float *gam  = (const float*)d_in[10];
    const float *w1   = (const float*)d_in[11], *b1   = (const float*)d_in[12];
    const float *w2   = (const float*)d_in[13], *b2   = (const float*)d_in[14];
    const float *ln1g = (const float*)d_in[15], *ln1b = (const float*)d_in[16];
    const float *ln2g = (const float*)d_in[17], *ln2b = (const float*)d_in[18];
    const float *lncg = (const float*)d_in[19], *lncb = (const float*)d_in[20];

    float* out_h = (float*)d_out;
    float* out_z = out_h + (size_t)4096 * 1024;
    float* h1    = out_h;

    // 0. weight conversion (f32 [K][N] -> bf16 [N][K])
    transpose_f2b<<<dim3(16, 16), 256, 0, stream>>>(wv, wvT, 1024, 1024);
    transpose_f2b<<<dim3(16, 16), 256, 0, stream>>>(wo, woT, 1024, 1024);
    transpose_f2b<<<dim3(64, 16), 256, 0, stream>>>(w1, w1T, 1024, 4096);
    transpose_f2b<<<dim3(16, 64), 256, 0, stream>>>(w2, w2T, 4096, 1024);
    transpose_f2b<<<dim3(1, 16),  256, 0, stream>>>(wcn, wcnT, 1024, 64);

    // 1. hn = LN1(h)
    ln_rows<float><<<4096, 256, 0, stream>>>(h, ln1g, ln1b, hn);
    // 2. packed attention operands from z (exp2-domain)
    zh_kernel<<<4096, 256, 0, stream>>>(z, wca, bca, gam, zq_pack, zk_pack);
    // 3. value = hn @ wv + bv           (128x64 tiles, BK=128, 512 blocks)
    gemm_kernel<0, 4, 2, 128, USH, USH><<<dim3(32, 16), 256, 0, stream>>>(hn, wvT, bv, (const USH*)nullptr, value, 4096, 1024, 1024);
    // 4. z_next = hn @ wcn + bcn        (MFMA, 32x32 tiles, 256 blocks)
    gemm_kernel<0, 1, 1, 64, float, float><<<dim3(128, 2), 256, 0, stream>>>(hn, wcnT, bcn, (const float*)nullptr, znext, 4096, 64, 1024);
    // 5. attention (q-split 64-row blocks, key-split waves, 4 blocks/CU)
    attn12_kernel<<<dim3(32, 32), 512, 0, stream>>>(zq_pack, zk_pack, value, attn_o);
    // 6. h1 = h + attn_o @ wo + bo      (128x64, BK=128, out f32 -> d_out)
    gemm_kernel<1, 4, 2, 128, float, float><<<dim3(32, 16), 256, 0, stream>>>(attn_o, woT, bo, h, h1, 4096, 1024, 1024);
    // 7. hn2 = LN2(h1)
    ln_rows<float><<<4096, 256, 0, stream>>>(h1, ln2g, ln2b, hn2);
    // 8. mid = gelu(hn2 @ w1 + b1)      (128x128, BK=64, 1024 blocks 4/CU)
    gemm_kernel<2, 4, 4, 64, USH, USH><<<dim3(32, 32), 256, 0, stream>>>(hn2, w1T, b1, (const USH*)nullptr, mid, 4096, 4096, 1024);
    // 9. out_h = h1 + mid @ w2 + b2     (128x64, BK=128, res==out same-thread)
    gemm_kernel<3, 4, 2, 128, float, float><<<dim3(32, 16), 256, 0, stream>>>(mid, w2T, b2, h1, out_h, 4096, 1024, 4096);
    // 10. out_z = LN(z + znext)
    lnc_kernel<<<4096, 64, 0, stream>>>(z, znext, lncg, lncb, out_z);
}

// Round 9
// 355.687 us; speedup vs baseline: 1.0202x; 1.0202x over previous
//
#include <hip/hip_runtime.h>

#define USH unsigned short

// ---------- bf16 helpers (storage = unsigned short) ----------
__device__ __forceinline__ float b2f(USH u) {
    union { unsigned int i; float f; } x; x.i = ((unsigned int)u) << 16; return x.f;
}
__device__ __forceinline__ USH f2b(float f) {
    union { float f; unsigned int i; } x; x.f = f;
    unsigned int r = x.i + (0x7fffu + ((x.i >> 16) & 1u));  // RNE
    return (USH)(r >> 16);
}
__device__ __forceinline__ float ldf(const USH* p)  { return b2f(*p); }
__device__ __forceinline__ float ldf(const float* p){ return *p; }
__device__ __forceinline__ void stf(USH* p, float v)  { *p = f2b(v); }
__device__ __forceinline__ void stf(float* p, float v){ *p = v; }

// async global->LDS, 16B per lane (dest = wave-uniform base + lane*16)
#define GLOAD16(gp, lp) __builtin_amdgcn_global_load_lds(                     \
    (const __attribute__((address_space(1))) void*)(gp),                      \
    (__attribute__((address_space(3))) void*)(lp), 16, 0, 0)

typedef __attribute__((ext_vector_type(8))) __bf16 bf16x8;
typedef __attribute__((ext_vector_type(4))) float  floatx4;

// =====================================================================
// Weight transpose+convert: W[K][N] f32 -> WT[N][K] bf16.
// =====================================================================
__global__ __launch_bounds__(256) void transpose_f2b(const float* __restrict__ W,
                                                     USH* __restrict__ WT,
                                                     int K, int N) {
    __shared__ USH t[64][72];
    int n0 = blockIdx.x * 64, k0 = blockIdx.y * 64;
    int tid = threadIdx.x;
    int kr = tid >> 4, nc = (tid & 15) * 4;
#pragma unroll
    for (int r = 0; r < 4; r++) {
        int k = kr + r * 16;
        float4 v = *(const float4*)(W + (size_t)(k0 + k) * N + n0 + nc);
        t[nc + 0][k] = f2b(v.x); t[nc + 1][k] = f2b(v.y);
        t[nc + 2][k] = f2b(v.z); t[nc + 3][k] = f2b(v.w);
    }
    __syncthreads();
    int nr = tid >> 2, kc = (tid & 3) * 8;
#pragma unroll
    for (int r = 0; r < 2; r++) {
        int k = kc + r * 32;
        *(int4*)(WT + (size_t)(n0 + nr) * K + k0 + k) = *(const int4*)&t[nr][k];
    }
}

// =====================================================================
// LayerNorm rows of 1024. block=256, one block/row.
// =====================================================================
template <typename TX>
__global__ __launch_bounds__(256) void ln_rows(const TX* __restrict__ x,
                                               const float* __restrict__ g,
                                               const float* __restrict__ bb,
                                               USH* __restrict__ y) {
    int row = blockIdx.x, tid = threadIdx.x;
    const TX* xr = x + (size_t)row * 1024 + tid * 4;
    float v[4];
#pragma unroll
    for (int i = 0; i < 4; i++) v[i] = ldf(xr + i);
    float s  = v[0] + v[1] + v[2] + v[3];
    float ss = v[0]*v[0] + v[1]*v[1] + v[2]*v[2] + v[3]*v[3];
#pragma unroll
    for (int o = 32; o; o >>= 1) { s += __shfl_down(s, o); ss += __shfl_down(ss, o); }
    __shared__ float red[10];
    int w = tid >> 6;
    if ((tid & 63) == 0) { red[w] = s; red[4 + w] = ss; }
    __syncthreads();
    if (tid == 0) {
        float S = red[0] + red[1] + red[2] + red[3];
        float SS = red[4] + red[5] + red[6] + red[7];
        float mean = S * (1.f / 1024.f);
        float var  = SS * (1.f / 1024.f) - mean * mean;
        red[8] = mean; red[9] = rsqrtf(var + 1e-5f);
    }
    __syncthreads();
    float mean = red[8], rstd = red[9];
    USH* yr = y + (size_t)row * 1024 + tid * 4;
#pragma unroll
    for (int i = 0; i < 4; i++) {
        int c = tid * 4 + i;
        yr[i] = f2b((v[i] - mean) * rstd * g[c] + bb[c]);
    }
}

// =====================================================================
// zh = z @ wca + bca, emitting packed MFMA operand rows (head-major),
// exp2-domain fold (gvl = softplus(gamma)*log2e).
// =====================================================================
__global__ __launch_bounds__(256) void zh_kernel(const float* __restrict__ z,
                                                 const float* __restrict__ wca,
                                                 const float* __restrict__ bca,
                                                 const float* __restrict__ gamma,
                                                 USH* __restrict__ zq_pack,
                                                 USH* __restrict__ zk_pack) {
    int row = blockIdx.x, n = threadIdx.x;
    __shared__ float zrow[64];
    if (n < 64) zrow[n] = z[(size_t)row * 64 + n];
    __syncthreads();
    float s = bca[n];
#pragma unroll 8
    for (int k = 0; k < 64; k++) s = fmaf(zrow[k], wca[(size_t)k * 256 + n], s);
    int h = n >> 4, c = n & 15;
    float gvl = log1pf(__expf(gamma[h])) * 1.44269504f;  // softplus * log2e
    USH u = f2b(s);
    float sv = b2f(u);
    float sq = sv * sv;
    sq += __shfl_xor(sq, 1); sq += __shfl_xor(sq, 2);
    sq += __shfl_xor(sq, 4); sq += __shfl_xor(sq, 8);
    size_t base = ((size_t)h * 4096 + row) * 32;
    zk_pack[base + c] = u;
    zq_pack[base + c] = f2b(2.f * gvl * s);
    if (c == 0) {
        USH hi = f2b(sq);
        float lo = sq - b2f(hi);
        unsigned int kw0 = 0x3F80u | ((unsigned int)hi << 16);
        unsigned int kw1 = (unsigned int)f2b(lo);
        uint4 kv = {kw0, kw1, 0u, 0u};
        uint4 zz = {0u, 0u, 0u, 0u};
        *(uint4*)(zk_pack + base + 16) = kv;
        *(uint4*)(zk_pack + base + 24) = zz;
        unsigned int qw0 = (unsigned int)f2b(-gvl * sq) | ((unsigned int)f2b(-gvl) << 16);
        unsigned int qw1 = (unsigned int)f2b(-gvl);
        uint4 qv = {qw0, qw1, 0u, 0u};
        *(uint4*)(zq_pack + base + 16) = qv;
        *(uint4*)(zq_pack + base + 24) = zz;
    }
}

// =====================================================================
// MFMA GEMM v6: templated BK (64 or 128), XOR-swizzled gload_lds staging.
// KB=128 for the grid-capped N=1024 GEMMs; KB=64 for FFN1 (occupancy).
// EPI: 0 = plain | 1 = +res | 2 = gelu | 3 = +res
// =====================================================================
template <int EPI, int MI, int NI, int KB, typename TRES, typename TOUT>
__global__ __launch_bounds__(256) void gemm_kernel(const USH* __restrict__ A,
                                                   const USH* __restrict__ WT,
                                                   const float* __restrict__ bias,
                                                   const TRES* __restrict__ res,
                                                   TOUT* __restrict__ out,
                                                   int M, int N, int K) {
    constexpr int BM  = MI * 32;
    constexpr int BN  = NI * 32;
    constexpr int GR  = KB / 8;        // 16B granules per row
    constexpr int RPC = 2048 / KB;     // rows per 4KB staged chunk
    constexpr int ACH = BM / RPC;      // A chunks per K-step
    constexpr int BCH = BN / RPC;      // B chunks per K-step
    __shared__ __align__(16) USH lA[BM][KB];
    __shared__ __align__(16) USH lB[BN][KB];
    int tid = threadIdx.x;
    int lane = tid & 63, wave = tid >> 6;
    int wr = wave >> 1, wc = wave & 1;
    int quad = lane >> 4, l15 = lane & 15;
    int m0 = blockIdx.x * BM, n0 = blockIdx.y * BN;

    int srow = tid / GR;               // row within chunk
    int kg   = tid % GR;               // 16B granule within row
    int scol = (kg ^ (srow & 7)) * 8;  // swizzled source column

    const USH* gA = A + (size_t)(m0 + srow) * K + scol;
    const USH* gB = WT + (size_t)(n0 + srow) * K + scol;
    USH* lA0 = &lA[0][0] + tid * 8;    // lane*16B dest (linear)
    USH* lB0 = &lB[0][0] + tid * 8;
    int xo = (l15 & 7) * 8;            // read-side XOR

    floatx4 acc[MI][NI] = {};

    for (int k0 = 0; k0 < K; k0 += KB) {
#pragma unroll
        for (int c = 0; c < ACH; c++)
            GLOAD16(gA + (size_t)c * RPC * K + k0, lA0 + c * 2048);
#pragma unroll
        for (int c = 0; c < BCH; c++)
            GLOAD16(gB + (size_t)c * RPC * K + k0, lB0 + c * 2048);
        __syncthreads();

#pragma unroll
        for (int ks = 0; ks < KB / 32; ks++) {
            bf16x8 bfr[NI];
#pragma unroll
            for (int ni = 0; ni < NI; ni++)
                bfr[ni] = *(const bf16x8*)&lB[wc * (NI * 16) + ni * 16 + l15][(ks * 32 + quad * 8) ^ xo];
#pragma unroll
            for (int mi = 0; mi < MI; mi++) {
                bf16x8 afr = *(const bf16x8*)&lA[wr * (MI * 16) + mi * 16 + l15][(ks * 32 + quad * 8) ^ xo];
#pragma unroll
                for (int ni = 0; ni < NI; ni++)
                    acc[mi][ni] = __builtin_amdgcn_mfma_f32_16x16x32_bf16(afr, bfr[ni], acc[mi][ni], 0, 0, 0);
            }
        }
        __syncthreads();
    }

    float bias_v[NI];
#pragma unroll
    for (int ni = 0; ni < NI; ni++) bias_v[ni] = bias[n0 + wc * (NI * 16) + ni * 16 + l15];

#pragma unroll
    for (int mi = 0; mi < MI; mi++) {
#pragma unroll
        for (int r = 0; r < 4; r++) {
            int row = m0 + wr * (MI * 16) + mi * 16 + quad * 4 + r;
            size_t base = (size_t)row * N;
#pragma unroll
            for (int ni = 0; ni < NI; ni++) {
                int col = n0 + wc * (NI * 16) + ni * 16 + l15;
                float v = acc[mi][ni][r] + bias_v[ni];
                if (EPI == 2) {
                    // tanh-form GELU: v * sigmoid(1.5958*v + 0.07135*v^3)
                    float t = v * v;
                    float a = fmaf(t, -0.0713548162726f, -1.59576912161f);
                    v = v * __builtin_amdgcn_rcpf(1.f + __expf(v * a));
                }
                if (EPI == 1 || EPI == 3) v += ldf(res + base + col);
                stf(out + base + col, v);
            }
        }
    }
}

// =====================================================================
// Flash distance-attention v13: REGISTER-P via swapped QK^T.
// Shell = v11 (the 61 µs best: grid (32,16), 8 waves x 16 q-rows,
// dbuf K/V, 1 barrier/tile). [v12's q/key-split REVERTED: +47% occupancy
// but 2x staging traffic and 2 QK MFMA/barrier -> net -19%.]
// New: QK operands SWAPPED -- sacc[ni] = mfma(bk[ni], afragQ) -- dot
// products identical, but output transposes: lane holds
// P[q=l15][key=ni*16+quad*4+r], which IS the PV A-fragment layout under
// the V key-permutation sigma(key) = 8*((key>>2)&3) + 4*((key>>4)&1)
// + (key&3) per 32-key group (V stores key k at column sigma; P pack:
// ap[ks2] elem j = bf16(exp2(sacc[2*ks2+(j>>2)][j&3]))). The Pb LDS
// round-trip (4 b64 writes + 2 b128 reads per wave-tile, and the
// serial QK->LDS->PV dependency) is DELETED. LDS 28.7 KB. Numerics
// bit-identical to v11 (same dots, same truncation).
// =====================================================================
__global__ __launch_bounds__(512) void attn13_kernel(const USH* __restrict__ zq_pack,
                                                     const USH* __restrict__ zk_pack,
                                                     const USH* __restrict__ value,
                                                     USH* __restrict__ attn_out) {
    int b = blockIdx.x >> 4, h = blockIdx.x & 15;
    int q0 = blockIdx.y * 128;
    int tid = threadIdx.x, lane = tid & 63, wq = tid >> 6;   // wq 0..7
    int quad = lane >> 4, l15 = lane & 15;

    __shared__ __align__(16) USH KbT[2][64][40];
    __shared__ __align__(16) USH VbT[2][64][72];

    const size_t zrow0 = (size_t)b * 2048;
    const USH* zq = zq_pack + ((size_t)h * 4096 + zrow0) * 32;
    const USH* zk = zk_pack + ((size_t)h * 4096 + zrow0) * 32;
    const size_t vbase = zrow0 * 1024 + h * 64;

    // Q fragment (B-operand) direct from global -- read exactly once
    bf16x8 afragQ = *(const bf16x8*)(zq + (size_t)(q0 + wq * 16 + l15) * 32 + quad * 8);

    // ones fragment (bf16 1.0 x8)
    union { unsigned int u[4]; bf16x8 v; } onesu;
#pragma unroll
    for (int i = 0; i < 4; i++) onesu.u[i] = 0x3F803F80u;
    bf16x8 ones = onesu.v;

    floatx4 oacc[4] = {};
    floatx4 lacc = {};

    // staging roles: tid<256 -> V loader; tid>=256 -> K loader
    // V: thread handles CONSECUTIVE keys (key2, key2+1); the packed
    // dword lands at sigma column cb (sigma-adjacent pair).
    int kp   = tid & 31;
    int key2 = kp * 2;
    int dh0  = (tid >> 5) * 8;          // (V role; 0..56)
    int lg   = key2 >> 5, ll = key2 & 31;
    int cb   = lg * 32 + ((ll >> 2) & 3) * 8 + ((ll >> 4) & 1) * 4 + (ll & 3);
    int krow = (tid - 256) >> 2, kc0 = ((tid - 256) & 3) * 8;
    int4 vta, vtb; uint4 kreg;

    // ---- prologue: tile 0 -> LDS buf0; tile 1 -> regs ----
    if (tid < 256) {
        const USH* s0 = value + vbase + (size_t)key2 * 1024 + dh0;
        vta = *(const int4*)s0;
        vtb = *(const int4*)(s0 + 1024);
        const USH* ua = (const USH*)&vta;
        const USH* ub = (const USH*)&vtb;
#pragma unroll
        for (int e = 0; e < 8; e++) {
            unsigned int dw = (unsigned int)ua[e] | ((unsigned int)ub[e] << 16);
            *(unsigned int*)&VbT[0][dh0 + e][cb] = dw;
        }
        const USH* s1 = value + vbase + (size_t)(64 + key2) * 1024 + dh0;
        vta = *(const int4*)s1;
        vtb = *(const int4*)(s1 + 1024);
    } else {
        kreg = *(const uint4*)(zk + (size_t)krow * 32 + kc0);
        *(uint4*)&KbT[0][krow][kc0] = kreg;
        kreg = *(const uint4*)(zk + (size_t)(64 + krow) * 32 + kc0);
    }

    for (int it = 0; it < 32; it++) {
        int cur = it & 1;
        __syncthreads();   // tile `it` staged; prev tile's reads done
        // ---- write tile it+1 into buf^1; issue loads for tile it+2 ----
        if (it + 1 < 32) {
            if (tid < 256) {
                const USH* ua = (const USH*)&vta;
                const USH* ub = (const USH*)&vtb;
#pragma unroll
                for (int e = 0; e < 8; e++) {
                    unsigned int dw = (unsigned int)ua[e] | ((unsigned int)ub[e] << 16);
                    *(unsigned int*)&VbT[cur ^ 1][dh0 + e][cb] = dw;
                }
                if (it + 2 < 32) {
                    const USH* s0 = value + vbase + (size_t)((it + 2) * 64 + key2) * 1024 + dh0;
                    vta = *(const int4*)s0;
                    vtb = *(const int4*)(s0 + 1024);
                }
            } else {
                *(uint4*)&KbT[cur ^ 1][krow][kc0] = kreg;
                if (it + 2 < 32)
                    kreg = *(const uint4*)(zk + (size_t)((it + 2) * 64 + krow) * 32 + kc0);
            }
        }

        // ---- QK^T, SWAPPED operands: lane holds P[q=l15][key-slice] ----
        floatx4 sacc[4];
#pragma unroll
        for (int ni = 0; ni < 4; ni++) {
            bf16x8 bkn = *(const bf16x8*)&KbT[cur][ni * 16 + l15][quad * 8];
            floatx4 zz = {};
            sacc[ni] = __builtin_amdgcn_mfma_f32_16x16x32_bf16(bkn, afragQ, zz, 0, 0, 0);
        }

        // ---- exp2 + in-register P pack (A-fragment under sigma) ----
        bf16x8 ap[2];
#pragma unroll
        for (int ks2 = 0; ks2 < 2; ks2++) {
            union { unsigned int u[4]; bf16x8 v; } pu;
#pragma unroll
            for (int d = 0; d < 4; d++) {
                int hi = d >> 1;
                union { float f; unsigned int i; } a, c;
                a.f = exp2f(sacc[2 * ks2 + hi][(d & 1) * 2 + 0]);
                c.f = exp2f(sacc[2 * ks2 + hi][(d & 1) * 2 + 1]);
                pu.u[d] = (a.i >> 16) | (c.i & 0xFFFF0000u);
            }
            ap[ks2] = pu.v;
        }

        // ---- PV + rowsum, P straight from registers ----
#pragma unroll
        for (int ks2 = 0; ks2 < 2; ks2++) {
            bf16x8 bv[4];
#pragma unroll
            for (int nd = 0; nd < 4; nd++)
                bv[nd] = *(const bf16x8*)&VbT[cur][nd * 16 + l15][ks2 * 32 + quad * 8];
#pragma unroll
            for (int nd = 0; nd < 4; nd++)
                oacc[nd] = __builtin_amdgcn_mfma_f32_16x16x32_bf16(ap[ks2], bv[nd], oacc[nd], 0, 0, 0);
            lacc = __builtin_amdgcn_mfma_f32_16x16x32_bf16(ap[ks2], ones, lacc, 0, 0, 0);
        }
    }

    // ---- epilogue: lacc holds the rowsum in every column ----
#pragma unroll
    for (int r = 0; r < 4; r++) {
        float inv = 1.f / lacc[r];
        int row = q0 + wq * 16 + quad * 4 + r;
        USH* o = attn_out + (zrow0 + row) * 1024 + h * 64;
#pragma unroll
        for (int nd = 0; nd < 4; nd++) o[nd * 16 + l15] = f2b(oacc[nd][r] * inv);
    }
}

// =====================================================================
// z_out = LN(z + z_next) over rows of 64. block = 64 (one wave) per row.
// =====================================================================
__global__ __launch_bounds__(64) void lnc_kernel(const float* __restrict__ z,
                                                 const float* __restrict__ zn,
                                                 const float* __restrict__ g,
                                                 const float* __restrict__ bb,
                                                 float* __restrict__ out) {
    int row = blockIdx.x, t = threadIdx.x;
    float v = z[(size_t)row * 64 + t] + zn[(size_t)row * 64 + t];
    float s = v, ss = v * v;
#pragma unroll
    for (int o = 32; o; o >>= 1) { s += __shfl_xor(s, o); ss += __shfl_xor(ss, o); }
    float mean = s * (1.f / 64.f);
    float rstd = rsqrtf(ss * (1.f / 64.f) - mean * mean + 1e-5f);
    out[(size_t)row * 64 + t] = (v - mean) * rstd * g[t] + bb[t];
}

// =====================================================================
extern "C" void kernel_launch(void* const* d_in, const int* in_sizes, int n_in,
                              void* d_out, int out_size, void* d_ws, size_t ws_size,
                              hipStream_t stream) {
    // workspace layout (61 MB):
    //   [0,8M)    value    [8,16M) attn_o    [16,20M) zq_pack
    //   [20,24M)  zk_pack  [24,32M) hn
    //   [0,32M)   mid (overlays, written step 8)
    //   [32,40M)  hn2   [40,41M) znext
    //   [41,43M)  wvT  [43,45M) woT  [45,53M) w1T  [53,61M) w2T
    //   wcnT (128K) borrows the head of attn_o: written step 0, read
    //   step 4, overwritten step 5.
    // h1 (f32) lives in d_out's h region.
    char* p = (char*)d_ws;
    USH*   value   = (USH*)(p);
    USH*   attn_o  = (USH*)(p + ((size_t)8  << 20));
    USH*   wcnT    = (USH*)(p + ((size_t)8  << 20));   // overlay, pre-step-5
    USH*   zq_pack = (USH*)(p + ((size_t)16 << 20));
    USH*   zk_pack = (USH*)(p + ((size_t)20 << 20));
    USH*   hn      = (USH*)(p + ((size_t)24 << 20));
    USH*   mid     = (USH*)(p);
    USH*   hn2     = (USH*)(p + ((size_t)32 << 20));
    float* znext   = (float*)(p + ((size_t)40 << 20));
    USH*   wvT     = (USH*)(p + ((size_t)41 << 20));
    USH*   woT     = (USH*)(p + ((size_t)43 << 20));
    USH*   w1T     = (USH*)(p + ((size_t)45 << 20));
    USH*   w2T     = (USH*)(p + ((size_t)53 << 20));

    const float *h    = (const float*)d_in[0],  *z    = (const float*)d_in[1];
    const float *wv   = (const float*)d_in[2],  *bv   = (const float*)d_in[3];
    const float *wca  = (const float*)d_in[4],  *bca  = (const float*)d_in[5];
    const float *wcn  = (const float*)d_in[6],  *bcn  = (const float*)d_in[7];
    const float *wo   = (const float*)d_in[8],  *bo   = (const float*)d_in[9];
    const float *gam  = (const float*)d_in[10];
    const float *w1   = (const float*)d_in[11], *b1   = (const float*)d_in[12];
    const float *w2   = (const float*)d_in[13], *b2   = (const float*)d_in[14];
    const float *ln1g = (const float*)d_in[15], *ln1b = (const float*)d_in[16];
    const float *ln2g = (const float*)d_in[17], *ln2b = (const float*)d_in[18];
    const float *lncg = (const float*)d_in[19], *lncb = (const float*)d_in[20];

    float* out_h = (float*)d_out;
    float* out_z = out_h + (size_t)4096 * 1024;
    float* h1    = out_h;

    // 0. weight conversion (f32 [K][N] -> bf16 [N][K])
    transpose_f2b<<<dim3(16, 16), 256, 0, stream>>>(wv, wvT, 1024, 1024);
    transpose_f2b<<<dim3(16, 16), 256, 0, stream>>>(wo, woT, 1024, 1024);
    transpose_f2b<<<dim3(64, 16), 256, 0, stream>>>(w1, w1T, 1024, 4096);
    transpose_f2b<<<dim3(16, 64), 256, 0, stream>>>(w2, w2T, 4096, 1024);
    transpose_f2b<<<dim3(1, 16),  256, 0, stream>>>(wcn, wcnT, 1024, 64);

    // 1. hn = LN1(h)
    ln_rows<float><<<4096, 256, 0, stream>>>(h, ln1g, ln1b, hn);
    // 2. packed attention operands from z (exp2-domain)
    zh_kernel<<<4096, 256, 0, stream>>>(z, wca, bca, gam, zq_pack, zk_pack);
    // 3. value = hn @ wv + bv           (128x64 tiles, BK=128, 512 blocks)
    gemm_kernel<0, 4, 2, 128, USH, USH><<<dim3(32, 16), 256, 0, stream>>>(hn, wvT, bv, (const USH*)nullptr, value, 4096, 1024, 1024);
    // 4. z_next = hn @ wcn + bcn        (MFMA, 32x32 tiles, 256 blocks)
    gemm_kernel<0, 1, 1, 64, float, float><<<dim3(128, 2), 256, 0, stream>>>(hn, wcnT, bcn, (const float*)nullptr, znext, 4096, 64, 1024);
    // 5. attention (register-P via swapped QK, dbuf K/V, 1 barrier/tile)
    attn13_kernel<<<dim3(32, 16), 512, 0, stream>>>(zq_pack, zk_pack, value, attn_o);
    // 6. h1 = h + attn_o @ wo + bo      (128x64, BK=128, out f32 -> d_out)
    gemm_kernel<1, 4, 2, 128, float, float><<<dim3(32, 16), 256, 0, stream>>>(attn_o, woT, bo, h, h1, 4096, 1024, 1024);
    // 7. hn2 = LN2(h1)
    ln_rows<float><<<4096, 256, 0, stream>>>(h1, ln2g, ln2b, hn2);
    // 8. mid = gelu(hn2 @ w1 + b1)      (128x128, BK=64, 1024 blocks 4/CU)
    gemm_kernel<2, 4, 4, 64, USH, USH><<<dim3(32, 32), 256, 0, stream>>>(hn2, w1T, b1, (const USH*)nullptr, mid, 4096, 4096, 1024);
    // 9. out_h = h1 + mid @ w2 + b2     (128x64, BK=128, res==out same-thread)
    gemm_kernel<3, 4, 2, 128, float, float><<<dim3(32, 16), 256, 0, stream>>>(mid, w2T, b2, h1, out_h, 4096, 1024, 4096);
    // 10. out_z = LN(z + znext)
    lnc_kernel<<<4096, 64, 0, stream>>>(z, znext, lncg, lncb, out_z);
}

// Round 11
// 352.483 us; speedup vs baseline: 1.0295x; 1.0091x over previous
//
#include <hip/hip_runtime.h>

#define USH unsigned short

// ---------- bf16 helpers (storage = unsigned short) ----------
__device__ __forceinline__ float b2f(USH u) {
    union { unsigned int i; float f; } x; x.i = ((unsigned int)u) << 16; return x.f;
}
__device__ __forceinline__ USH f2b(float f) {
    union { float f; unsigned int i; } x; x.f = f;
    unsigned int r = x.i + (0x7fffu + ((x.i >> 16) & 1u));  // RNE
    return (USH)(r >> 16);
}
__device__ __forceinline__ float ldf(const USH* p)  { return b2f(*p); }
__device__ __forceinline__ float ldf(const float* p){ return *p; }
__device__ __forceinline__ void stf(USH* p, float v)  { *p = f2b(v); }
__device__ __forceinline__ void stf(float* p, float v){ *p = v; }

// async global->LDS, 16B per lane (dest = wave-uniform base + lane*16)
#define GLOAD16(gp, lp) __builtin_amdgcn_global_load_lds(                     \
    (const __attribute__((address_space(1))) void*)(gp),                      \
    (__attribute__((address_space(3))) void*)(lp), 16, 0, 0)

typedef __attribute__((ext_vector_type(8))) __bf16 bf16x8;
typedef __attribute__((ext_vector_type(4))) float  floatx4;

// =====================================================================
// Weight transpose+convert: W[K][N] f32 -> WT[N][K] bf16.
// =====================================================================
__global__ __launch_bounds__(256) void transpose_f2b(const float* __restrict__ W,
                                                     USH* __restrict__ WT,
                                                     int K, int N) {
    __shared__ USH t[64][72];
    int n0 = blockIdx.x * 64, k0 = blockIdx.y * 64;
    int tid = threadIdx.x;
    int kr = tid >> 4, nc = (tid & 15) * 4;
#pragma unroll
    for (int r = 0; r < 4; r++) {
        int k = kr + r * 16;
        float4 v = *(const float4*)(W + (size_t)(k0 + k) * N + n0 + nc);
        t[nc + 0][k] = f2b(v.x); t[nc + 1][k] = f2b(v.y);
        t[nc + 2][k] = f2b(v.z); t[nc + 3][k] = f2b(v.w);
    }
    __syncthreads();
    int nr = tid >> 2, kc = (tid & 3) * 8;
#pragma unroll
    for (int r = 0; r < 2; r++) {
        int k = kc + r * 32;
        *(int4*)(WT + (size_t)(n0 + nr) * K + k0 + k) = *(const int4*)&t[nr][k];
    }
}

// =====================================================================
// LayerNorm rows of 1024. block=256, one block/row.
// =====================================================================
template <typename TX>
__global__ __launch_bounds__(256) void ln_rows(const TX* __restrict__ x,
                                               const float* __restrict__ g,
                                               const float* __restrict__ bb,
                                               USH* __restrict__ y) {
    int row = blockIdx.x, tid = threadIdx.x;
    const TX* xr = x + (size_t)row * 1024 + tid * 4;
    float v[4];
#pragma unroll
    for (int i = 0; i < 4; i++) v[i] = ldf(xr + i);
    float s  = v[0] + v[1] + v[2] + v[3];
    float ss = v[0]*v[0] + v[1]*v[1] + v[2]*v[2] + v[3]*v[3];
#pragma unroll
    for (int o = 32; o; o >>= 1) { s += __shfl_down(s, o); ss += __shfl_down(ss, o); }
    __shared__ float red[10];
    int w = tid >> 6;
    if ((tid & 63) == 0) { red[w] = s; red[4 + w] = ss; }
    __syncthreads();
    if (tid == 0) {
        float S = red[0] + red[1] + red[2] + red[3];
        float SS = red[4] + red[5] + red[6] + red[7];
        float mean = S * (1.f / 1024.f);
        float var  = SS * (1.f / 1024.f) - mean * mean;
        red[8] = mean; red[9] = rsqrtf(var + 1e-5f);
    }
    __syncthreads();
    float mean = red[8], rstd = red[9];
    USH* yr = y + (size_t)row * 1024 + tid * 4;
#pragma unroll
    for (int i = 0; i < 4; i++) {
        int c = tid * 4 + i;
        yr[i] = f2b((v[i] - mean) * rstd * g[c] + bb[c]);
    }
}

// =====================================================================
// zh = z @ wca + bca, emitting packed MFMA operand rows (head-major),
// exp2-domain fold (gvl = softplus(gamma)*log2e).
// =====================================================================
__global__ __launch_bounds__(256) void zh_kernel(const float* __restrict__ z,
                                                 const float* __restrict__ wca,
                                                 const float* __restrict__ bca,
                                                 const float* __restrict__ gamma,
                                                 USH* __restrict__ zq_pack,
                                                 USH* __restrict__ zk_pack) {
    int row = blockIdx.x, n = threadIdx.x;
    __shared__ float zrow[64];
    if (n < 64) zrow[n] = z[(size_t)row * 64 + n];
    __syncthreads();
    float s = bca[n];
#pragma unroll 8
    for (int k = 0; k < 64; k++) s = fmaf(zrow[k], wca[(size_t)k * 256 + n], s);
    int h = n >> 4, c = n & 15;
    float gvl = log1pf(__expf(gamma[h])) * 1.44269504f;  // softplus * log2e
    USH u = f2b(s);
    float sv = b2f(u);
    float sq = sv * sv;
    sq += __shfl_xor(sq, 1); sq += __shfl_xor(sq, 2);
    sq += __shfl_xor(sq, 4); sq += __shfl_xor(sq, 8);
    size_t base = ((size_t)h * 4096 + row) * 32;
    zk_pack[base + c] = u;
    zq_pack[base + c] = f2b(2.f * gvl * s);
    if (c == 0) {
        USH hi = f2b(sq);
        float lo = sq - b2f(hi);
        unsigned int kw0 = 0x3F80u | ((unsigned int)hi << 16);
        unsigned int kw1 = (unsigned int)f2b(lo);
        uint4 kv = {kw0, kw1, 0u, 0u};
        uint4 zz = {0u, 0u, 0u, 0u};
        *(uint4*)(zk_pack + base + 16) = kv;
        *(uint4*)(zk_pack + base + 24) = zz;
        unsigned int qw0 = (unsigned int)f2b(-gvl * sq) | ((unsigned int)f2b(-gvl) << 16);
        unsigned int qw1 = (unsigned int)f2b(-gvl);
        uint4 qv = {qw0, qw1, 0u, 0u};
        *(uint4*)(zq_pack + base + 16) = qv;
        *(uint4*)(zq_pack + base + 24) = zz;
    }
}

// =====================================================================
// MFMA GEMM v6: templated BK (64 or 128), XOR-swizzled gload_lds staging.
// KB=128 for the grid-capped N=1024 GEMMs; KB=64 for FFN1 (occupancy).
// EPI: 0 = plain | 1 = +res | 2 = gelu | 3 = +res
// =====================================================================
template <int EPI, int MI, int NI, int KB, typename TRES, typename TOUT>
__global__ __launch_bounds__(256) void gemm_kernel(const USH* __restrict__ A,
                                                   const USH* __restrict__ WT,
                                                   const float* __restrict__ bias,
                                                   const TRES* __restrict__ res,
                                                   TOUT* __restrict__ out,
                                                   int M, int N, int K) {
    constexpr int BM  = MI * 32;
    constexpr int BN  = NI * 32;
    constexpr int GR  = KB / 8;        // 16B granules per row
    constexpr int RPC = 2048 / KB;     // rows per 4KB staged chunk
    constexpr int ACH = BM / RPC;      // A chunks per K-step
    constexpr int BCH = BN / RPC;      // B chunks per K-step
    __shared__ __align__(16) USH lA[BM][KB];
    __shared__ __align__(16) USH lB[BN][KB];
    int tid = threadIdx.x;
    int lane = tid & 63, wave = tid >> 6;
    int wr = wave >> 1, wc = wave & 1;
    int quad = lane >> 4, l15 = lane & 15;
    int m0 = blockIdx.x * BM, n0 = blockIdx.y * BN;

    int srow = tid / GR;               // row within chunk
    int kg   = tid % GR;               // 16B granule within row
    int scol = (kg ^ (srow & 7)) * 8;  // swizzled source column

    const USH* gA = A + (size_t)(m0 + srow) * K + scol;
    const USH* gB = WT + (size_t)(n0 + srow) * K + scol;
    USH* lA0 = &lA[0][0] + tid * 8;    // lane*16B dest (linear)
    USH* lB0 = &lB[0][0] + tid * 8;
    int xo = (l15 & 7) * 8;            // read-side XOR

    floatx4 acc[MI][NI] = {};

    for (int k0 = 0; k0 < K; k0 += KB) {
#pragma unroll
        for (int c = 0; c < ACH; c++)
            GLOAD16(gA + (size_t)c * RPC * K + k0, lA0 + c * 2048);
#pragma unroll
        for (int c = 0; c < BCH; c++)
            GLOAD16(gB + (size_t)c * RPC * K + k0, lB0 + c * 2048);
        __syncthreads();

#pragma unroll
        for (int ks = 0; ks < KB / 32; ks++) {
            bf16x8 bfr[NI];
#pragma unroll
            for (int ni = 0; ni < NI; ni++)
                bfr[ni] = *(const bf16x8*)&lB[wc * (NI * 16) + ni * 16 + l15][(ks * 32 + quad * 8) ^ xo];
#pragma unroll
            for (int mi = 0; mi < MI; mi++) {
                bf16x8 afr = *(const bf16x8*)&lA[wr * (MI * 16) + mi * 16 + l15][(ks * 32 + quad * 8) ^ xo];
#pragma unroll
                for (int ni = 0; ni < NI; ni++)
                    acc[mi][ni] = __builtin_amdgcn_mfma_f32_16x16x32_bf16(afr, bfr[ni], acc[mi][ni], 0, 0, 0);
            }
        }
        __syncthreads();
    }

    float bias_v[NI];
#pragma unroll
    for (int ni = 0; ni < NI; ni++) bias_v[ni] = bias[n0 + wc * (NI * 16) + ni * 16 + l15];

#pragma unroll
    for (int mi = 0; mi < MI; mi++) {
#pragma unroll
        for (int r = 0; r < 4; r++) {
            int row = m0 + wr * (MI * 16) + mi * 16 + quad * 4 + r;
            size_t base = (size_t)row * N;
#pragma unroll
            for (int ni = 0; ni < NI; ni++) {
                int col = n0 + wc * (NI * 16) + ni * 16 + l15;
                float v = acc[mi][ni][r] + bias_v[ni];
                if (EPI == 2) {
                    // tanh-form GELU: v * sigmoid(1.5958*v + 0.07135*v^3)
                    float t = v * v;
                    float a = fmaf(t, -0.0713548162726f, -1.59576912161f);
                    v = v * __builtin_amdgcn_rcpf(1.f + __expf(v * a));
                }
                if (EPI == 1 || EPI == 3) v += ldf(res + base + col);
                stf(out + base + col, v);
            }
        }
    }
}

// =====================================================================
// Flash distance-attention v15: register-P (swapped QK^T) + KVBLK=128.
// v15 = v14 with the K-staging coverage bug FIXED: v14's K loader put
// only 8 USH/thread into a 128-row x 32-USH tile (half the tile --
// including the ks fold terms at cols 16..18 -- was never written ->
// NaN). Fix: keep v13's verified per-row pattern (4 threads/row, one
// uint4 each) and give each K thread TWO rows (krow, krow+64).
// Everything else as designed in R10: barriers 32 -> 16, 28 MFMA per
// wave per barrier, same total work, 54 KB LDS, 2 blocks/CU.
// sigma-perm over 4 key-groups: col(K) = (K>>5)*32 + ((K>>2)&3)*8 +
// ((K>>4)&1)*4 + (K&3). Key accumulation order unchanged -> output
// numerically identical to v13.
// =====================================================================
__global__ __launch_bounds__(512) void attn15_kernel(const USH* __restrict__ zq_pack,
                                                     const USH* __restrict__ zk_pack,
                                                     const USH* __restrict__ value,
                                                     USH* __restrict__ attn_out) {
    int b = blockIdx.x >> 4, h = blockIdx.x & 15;
    int q0 = blockIdx.y * 128;
    int tid = threadIdx.x, lane = tid & 63, wq = tid >> 6;   // wq 0..7
    int quad = lane >> 4, l15 = lane & 15;

    __shared__ __align__(16) USH KbT[2][128][40];   // 20480 B
    __shared__ __align__(16) USH VbT[2][64][136];   // 34816 B

    const size_t zrow0 = (size_t)b * 2048;
    const USH* zq = zq_pack + ((size_t)h * 4096 + zrow0) * 32;
    const USH* zk = zk_pack + ((size_t)h * 4096 + zrow0) * 32;
    const size_t vbase = zrow0 * 1024 + h * 64;

    // Q fragment (B-operand) direct from global -- read exactly once
    bf16x8 afragQ = *(const bf16x8*)(zq + (size_t)(q0 + wq * 16 + l15) * 32 + quad * 8);

    // ones fragment (bf16 1.0 x8)
    union { unsigned int u[4]; bf16x8 v; } onesu;
#pragma unroll
    for (int i = 0; i < 4; i++) onesu.u[i] = 0x3F803F80u;
    bf16x8 ones = onesu.v;

    floatx4 oacc[4] = {};
    floatx4 lacc = {};

    // staging roles: tid<256 -> V loader; tid>=256 -> K loader.
    // V: thread (dhc = tid>>6, kp = tid&63): keys (2kp, 2kp+1), dh rows
    //    dh0..dh0+15; packed dword -> sigma column cb. Coverage:
    //    64 pairs x 4 dh-chunks x 32 USH = full 128x64 tile.
    // K: thread handles rows krow AND krow+64 (one uint4 at kc0 each) --
    //    4 threads/row x 8 USH x 2 rows = full 128x32 tile.
    int kp   = tid & 63;
    int key2 = kp * 2;
    int dh0  = (tid >> 6) * 16;
    int lg   = key2 >> 5, ll = key2 & 31;
    int cb   = lg * 32 + ((ll >> 2) & 3) * 8 + ((ll >> 4) & 1) * 4 + (ll & 3);
    int krow = (tid - 256) >> 2, kc0 = ((tid - 256) & 3) * 8;
    int4 vr[4]; uint4 kregA, kregB;

    // ---- prologue: tile 0 -> LDS buf0; tile 1 -> regs ----
    if (tid < 256) {
        const USH* s0 = value + vbase + (size_t)key2 * 1024 + dh0;
        vr[0] = *(const int4*)s0;
        vr[1] = *(const int4*)(s0 + 8);
        vr[2] = *(const int4*)(s0 + 1024);
        vr[3] = *(const int4*)(s0 + 1024 + 8);
        const USH* ua = (const USH*)&vr[0];
        const USH* ub = (const USH*)&vr[2];
#pragma unroll
        for (int e = 0; e < 16; e++) {
            unsigned int dw = (unsigned int)ua[e] | ((unsigned int)ub[e] << 16);
            *(unsigned int*)&VbT[0][dh0 + e][cb] = dw;
        }
        const USH* s1 = value + vbase + (size_t)(128 + key2) * 1024 + dh0;
        vr[0] = *(const int4*)s1;
        vr[1] = *(const int4*)(s1 + 8);
        vr[2] = *(const int4*)(s1 + 1024);
        vr[3] = *(const int4*)(s1 + 1024 + 8);
    } else {
        kregA = *(const uint4*)(zk + (size_t)krow * 32 + kc0);
        kregB = *(const uint4*)(zk + (size_t)(64 + krow) * 32 + kc0);
        *(uint4*)&KbT[0][krow][kc0] = kregA;
        *(uint4*)&KbT[0][64 + krow][kc0] = kregB;
        kregA = *(const uint4*)(zk + (size_t)(128 + krow) * 32 + kc0);
        kregB = *(const uint4*)(zk + (size_t)(128 + 64 + krow) * 32 + kc0);
    }

    for (int it = 0; it < 16; it++) {
        int cur = it & 1;
        __syncthreads();   // tile `it` staged; prev tile's reads done
        // ---- write tile it+1 into buf^1; issue loads for tile it+2 ----
        if (it + 1 < 16) {
            if (tid < 256) {
                const USH* ua = (const USH*)&vr[0];
                const USH* ub = (const USH*)&vr[2];
#pragma unroll
                for (int e = 0; e < 16; e++) {
                    unsigned int dw = (unsigned int)ua[e] | ((unsigned int)ub[e] << 16);
                    *(unsigned int*)&VbT[cur ^ 1][dh0 + e][cb] = dw;
                }
                if (it + 2 < 16) {
                    const USH* s0 = value + vbase + (size_t)((it + 2) * 128 + key2) * 1024 + dh0;
                    vr[0] = *(const int4*)s0;
                    vr[1] = *(const int4*)(s0 + 8);
                    vr[2] = *(const int4*)(s0 + 1024);
                    vr[3] = *(const int4*)(s0 + 1024 + 8);
                }
            } else {
                *(uint4*)&KbT[cur ^ 1][krow][kc0] = kregA;
                *(uint4*)&KbT[cur ^ 1][64 + krow][kc0] = kregB;
                if (it + 2 < 16) {
                    kregA = *(const uint4*)(zk + (size_t)((it + 2) * 128 + krow) * 32 + kc0);
                    kregB = *(const uint4*)(zk + (size_t)((it + 2) * 128 + 64 + krow) * 32 + kc0);
                }
            }
        }

        // ---- two 64-key halves per staged tile ----
#pragma unroll
        for (int kh = 0; kh < 2; kh++) {
            // QK^T, SWAPPED operands: lane holds P[q=l15][key-slice]
            floatx4 sacc[4];
#pragma unroll
            for (int ni = 0; ni < 4; ni++) {
                bf16x8 bkn = *(const bf16x8*)&KbT[cur][kh * 64 + ni * 16 + l15][quad * 8];
                floatx4 zz = {};
                sacc[ni] = __builtin_amdgcn_mfma_f32_16x16x32_bf16(bkn, afragQ, zz, 0, 0, 0);
            }

            // exp2 + in-register P pack (A-fragment under sigma)
            bf16x8 ap[2];
#pragma unroll
            for (int ks2 = 0; ks2 < 2; ks2++) {
                union { unsigned int u[4]; bf16x8 v; } pu;
#pragma unroll
                for (int d = 0; d < 4; d++) {
                    int hi = d >> 1;
                    union { float f; unsigned int i; } a, c;
                    a.f = exp2f(sacc[2 * ks2 + hi][(d & 1) * 2 + 0]);
                    c.f = exp2f(sacc[2 * ks2 + hi][(d & 1) * 2 + 1]);
                    pu.u[d] = (a.i >> 16) | (c.i & 0xFFFF0000u);
                }
                ap[ks2] = pu.v;
            }

            // PV + rowsum, P straight from registers
#pragma unroll
            for (int ks2 = 0; ks2 < 2; ks2++) {
                bf16x8 bv[4];
#pragma unroll
                for (int nd = 0; nd < 4; nd++)
                    bv[nd] = *(const bf16x8*)&VbT[cur][nd * 16 + l15][kh * 64 + ks2 * 32 + quad * 8];
#pragma unroll
                for (int nd = 0; nd < 4; nd++)
                    oacc[nd] = __builtin_amdgcn_mfma_f32_16x16x32_bf16(ap[ks2], bv[nd], oacc[nd], 0, 0, 0);
                lacc = __builtin_amdgcn_mfma_f32_16x16x32_bf16(ap[ks2], ones, lacc, 0, 0, 0);
            }
        }
    }

    // ---- epilogue: lacc holds the rowsum in every column ----
#pragma unroll
    for (int r = 0; r < 4; r++) {
        float inv = 1.f / lacc[r];
        int row = q0 + wq * 16 + quad * 4 + r;
        USH* o = attn_out + (zrow0 + row) * 1024 + h * 64;
#pragma unroll
        for (int nd = 0; nd < 4; nd++) o[nd * 16 + l15] = f2b(oacc[nd][r] * inv);
    }
}

// =====================================================================
// z_out = LN(z + z_next) over rows of 64. block = 64 (one wave) per row.
// =====================================================================
__global__ __launch_bounds__(64) void lnc_kernel(const float* __restrict__ z,
                                                 const float* __restrict__ zn,
                                                 const float* __restrict__ g,
                                                 const float* __restrict__ bb,
                                                 float* __restrict__ out) {
    int row = blockIdx.x, t = threadIdx.x;
    float v = z[(size_t)row * 64 + t] + zn[(size_t)row * 64 + t];
    float s = v, ss = v * v;
#pragma unroll
    for (int o = 32; o; o >>= 1) { s += __shfl_xor(s, o); ss += __shfl_xor(ss, o); }
    float mean = s * (1.f / 64.f);
    float rstd = rsqrtf(ss * (1.f / 64.f) - mean * mean + 1e-5f);
    out[(size_t)row * 64 + t] = (v - mean) * rstd * g[t] + bb[t];
}

// =====================================================================
extern "C" void kernel_launch(void* const* d_in, const int* in_sizes, int n_in,
                              void* d_out, int out_size, void* d_ws, size_t ws_size,
                              hipStream_t stream) {
    // workspace layout (61 MB):
    //   [0,8M)    value    [8,16M) attn_o    [16,20M) zq_pack
    //   [20,24M)  zk_pack  [24,32M) hn
    //   [0,32M)   mid (overlays, written step 8)
    //   [32,40M)  hn2   [40,41M) znext
    //   [41,43M)  wvT  [43,45M) woT  [45,53M) w1T  [53,61M) w2T
    //   wcnT (128K) borrows the head of attn_o: written step 0, read
    //   step 4, overwritten step 5.
    // h1 (f32) lives in d_out's h region.
    char* p = (char*)d_ws;
    USH*   value   = (USH*)(p);
    USH*   attn_o  = (USH*)(p + ((size_t)8  << 20));
    USH*   wcnT    = (USH*)(p + ((size_t)8  << 20));   // overlay, pre-step-5
    USH*   zq_pack = (USH*)(p + ((size_t)16 << 20));
    USH*   zk_pack = (USH*)(p + ((size_t)20 << 20));
    USH*   hn      = (USH*)(p + ((size_t)24 << 20));
    USH*   mid     = (USH*)(p);
    USH*   hn2     = (USH*)(p + ((size_t)32 << 20));
    float* znext   = (float*)(p + ((size_t)40 << 20));
    USH*   wvT     = (USH*)(p + ((size_t)41 << 20));
    USH*   woT     = (USH*)(p + ((size_t)43 << 20));
    USH*   w1T     = (USH*)(p + ((size_t)45 << 20));
    USH*   w2T     = (USH*)(p + ((size_t)53 << 20));

    const float *h    = (const float*)d_in[0],  *z    = (const float*)d_in[1];
    const float *wv   = (const float*)d_in[2],  *bv   = (const float*)d_in[3];
    const float *wca  = (const float*)d_in[4],  *bca  = (const float*)d_in[5];
    const float *wcn  = (const float*)d_in[6],  *bcn  = (const float*)d_in[7];
    const float *wo   = (const float*)d_in[8],  *bo   = (const float*)d_in[9];
    const float *gam  = (const float*)d_in[10];
    const float *w1   = (const float*)d_in[11], *b1   = (const float*)d_in[12];
    const float *w2   = (const float*)d_in[13], *b2   = (const float*)d_in[14];
    const float *ln1g = (const float*)d_in[15], *ln1b = (const float*)d_in[16];
    const float *ln2g = (const float*)d_in[17], *ln2b = (const float*)d_in[18];
    const float *lncg = (const float*)d_in[19], *lncb = (const float*)d_in[20];

    float* out_h = (float*)d_out;
    float* out_z = out_h + (size_t)4096 * 1024;
    float* h1    = out_h;

    // 0. weight conversion (f32 [K][N] -> bf16 [N][K])
    transpose_f2b<<<dim3(16, 16), 256, 0, stream>>>(wv, wvT, 1024, 1024);
    transpose_f2b<<<dim3(16, 16), 256, 0, stream>>>(wo, woT, 1024, 1024);
    transpose_f2b<<<dim3(64, 16), 256, 0, stream>>>(w1, w1T, 1024, 4096);
    transpose_f2b<<<dim3(16, 64), 256, 0, stream>>>(w2, w2T, 4096, 1024);
    transpose_f2b<<<dim3(1, 16),  256, 0, stream>>>(wcn, wcnT, 1024, 64);

    // 1. hn = LN1(h)
    ln_rows<float><<<4096, 256, 0, stream>>>(h, ln1g, ln1b, hn);
    // 2. packed attention operands from z (exp2-domain)
    zh_kernel<<<4096, 256, 0, stream>>>(z, wca, bca, gam, zq_pack, zk_pack);
    // 3. value = hn @ wv + bv           (128x64 tiles, BK=128, 512 blocks)
    gemm_kernel<0, 4, 2, 128, USH, USH><<<dim3(32, 16), 256, 0, stream>>>(hn, wvT, bv, (const USH*)nullptr, value, 4096, 1024, 1024);
    // 4. z_next = hn @ wcn + bcn        (MFMA, 32x32 tiles, 256 blocks)
    gemm_kernel<0, 1, 1, 64, float, float><<<dim3(128, 2), 256, 0, stream>>>(hn, wcnT, bcn, (const float*)nullptr, znext, 4096, 64, 1024);
    // 5. attention (register-P, KVBLK=128, 16 barriers) — 512 thr
    attn15_kernel<<<dim3(32, 16), 512, 0, stream>>>(zq_pack, zk_pack, value, attn_o);
    // 6. h1 = h + attn_o @ wo + bo      (128x64, BK=128, out f32 -> d_out)
    gemm_kernel<1, 4, 2, 128, float, float><<<dim3(32, 16), 256, 0, stream>>>(attn_o, woT, bo, h, h1, 4096, 1024, 1024);
    // 7. hn2 = LN2(h1)
    ln_rows<float><<<4096, 256, 0, stream>>>(h1, ln2g, ln2b, hn2);
    // 8. mid = gelu(hn2 @ w1 + b1)      (128x128, BK=64, 1024 blocks 4/CU)
    gemm_kernel<2, 4, 4, 64, USH, USH><<<dim3(32, 32), 256, 0, stream>>>(hn2, w1T, b1, (const USH*)nullptr, mid, 4096, 4096, 1024);
    // 9. out_h = h1 + mid @ w2 + b2     (128x64, BK=128, res==out same-thread)
    gemm_kernel<3, 4, 2, 128, float, float><<<dim3(32, 16), 256, 0, stream>>>(mid, w2T, b2, h1, out_h, 4096, 1024, 4096);
    // 10. out_z = LN(z + znext)
    lnc_kernel<<<4096, 64, 0, stream>>>(z, znext, lncg, lncb, out_z);
}